// Round 10
// baseline (805.640 us; speedup 1.0000x reference)
//
#include <hip/hip_runtime.h>
#include <stdint.h>

// y[m,o] = sum_k x[m,k]*(W8[o,k]-zero[o])*scale[o] + bias[o], M=8192 N=11008 K=4096.
// x ~= xs_m*(128*h + l) (h,l int8); G = xs_m*(128*Gh + Gl) via two i8 MFMA GEMMs
// sharing B-frags; y = scale*G - scale*zero*rowsum + bias.
// R10: ring-4 half-tile (K=64) pipeline. Per half h:
//   stage(h+3) -> s_waitcnt vmcnt(12)  [waits loads issued 3 phases ago only]
//   -> barrier -> {B frags (4 ds_read) ; A ping-pong: read A(mi+1) || 8 MFMA(mi)}
//   -> barrier.  Tail drains 12->8->4->0. Counted vmcnt + fine interleave
// together (R4 had only the former, R9 only the latter; both stuck at 49%).
// 64B-row LDS with R8's measured-conflict-free additive swizzle
// phys_slot=(logic+(row>>1))&3, staged via inverse-permuted global source.

#define M_DIM 8192
#define N_DIM 11008
#define K_DIM 4096
#define NH    (K_DIM / 64)    // 64 half-tiles
#define BUFH  32768           // ring buffer entry: Ah 8K | Al 8K | B 16K

typedef __attribute__((ext_vector_type(4))) int i32x4;

// ---------------- prep kernels ----------------

__global__ void convert_w_kernel(const int* __restrict__ w,
                                 int8_t* __restrict__ o, int n4) {
  int idx = blockIdx.x * blockDim.x + threadIdx.x;
  int stride = gridDim.x * blockDim.x;
  for (int i = idx; i < n4; i += stride) {
    int4 v = ((const int4*)w)[i];
    int r = (v.x & 255) | ((v.y & 255) << 8) | ((v.z & 255) << 16) | ((v.w & 255) << 24);
    ((int*)o)[i] = r;
  }
}

__global__ __launch_bounds__(256) void quantx_kernel(
    const float* __restrict__ x, int8_t* __restrict__ h8, int8_t* __restrict__ l8,
    float* __restrict__ xs, float* __restrict__ rsum) {
  const int row = blockIdx.x;
  const int t = threadIdx.x;
  const float4* px = (const float4*)(x + (size_t)row * K_DIM);
  float4 v[4];
  float mx = 0.f, sm = 0.f;
  #pragma unroll
  for (int i = 0; i < 4; ++i) {
    v[i] = px[i * 256 + t];
    mx = fmaxf(mx, fmaxf(fmaxf(fabsf(v[i].x), fabsf(v[i].y)),
                         fmaxf(fabsf(v[i].z), fabsf(v[i].w))));
    sm += v[i].x + v[i].y + v[i].z + v[i].w;
  }
  #pragma unroll
  for (int off = 32; off > 0; off >>= 1) {
    mx = fmaxf(mx, __shfl_down(mx, off));
    sm += __shfl_down(sm, off);
  }
  __shared__ float rmx[4], rsm[4];
  const int wv = t >> 6, ln = t & 63;
  if (ln == 0) { rmx[wv] = mx; rsm[wv] = sm; }
  __syncthreads();
  const float rowmax = fmaxf(fmaxf(rmx[0], rmx[1]), fmaxf(rmx[2], rmx[3]));
  if (t == 0) {
    xs[row] = rowmax > 0.f ? rowmax / 16256.f : 0.f;
    rsum[row] = rsm[0] + rsm[1] + rsm[2] + rsm[3];
  }
  const float inv = rowmax > 0.f ? 16256.f / rowmax : 0.f;
  int* hp = (int*)(h8 + (size_t)row * K_DIM);
  int* lp = (int*)(l8 + (size_t)row * K_DIM);
  #pragma unroll
  for (int i = 0; i < 4; ++i) {
    int q0 = (int)rintf(v[i].x * inv);
    int q1 = (int)rintf(v[i].y * inv);
    int q2 = (int)rintf(v[i].z * inv);
    int q3 = (int)rintf(v[i].w * inv);
    int h0 = (q0 + 64) >> 7, h1 = (q1 + 64) >> 7, h2 = (q2 + 64) >> 7, h3 = (q3 + 64) >> 7;
    int l0 = q0 - (h0 << 7), l1 = q1 - (h1 << 7), l2 = q2 - (h2 << 7), l3 = q3 - (h3 << 7);
    hp[i * 256 + t] = (h0 & 255) | ((h1 & 255) << 8) | ((h2 & 255) << 16) | ((h3 & 255) << 24);
    lp[i * 256 + t] = (l0 & 255) | ((l1 & 255) << 8) | ((l2 & 255) << 16) | ((l3 & 255) << 24);
  }
}

// ---------------- main GEMM ----------------

// stage half-tile h into ring[(h)&3]: per thread 1 Ah + 1 Al + 2 B loads.
// thread t owns row t>>2, phys slot t&3 -> LDS dest byte = t*16 (linear).
// global col = logical slot = ((t&3) - ((t>>3)&3)) & 3 (inverse of read swz).
__device__ __forceinline__ void stage_half(
    const int8_t* __restrict__ Ah, const int8_t* __restrict__ Al,
    const int8_t* __restrict__ Bw, size_t a_base, size_t b_base,
    int h, int trow, int scol, int wave, int8_t* smem) {
  int8_t* buf = smem + (h & 3) * BUFH;
  const int ks = h * 64;
  {
    const int8_t* g = Ah + a_base + (size_t)trow * K_DIM + ks + scol;
    __builtin_amdgcn_global_load_lds((const __attribute__((address_space(1))) void*)g,
        (__attribute__((address_space(3))) void*)(buf + wave * 1024), 16, 0, 0);
  }
  {
    const int8_t* g = Al + a_base + (size_t)trow * K_DIM + ks + scol;
    __builtin_amdgcn_global_load_lds((const __attribute__((address_space(1))) void*)g,
        (__attribute__((address_space(3))) void*)(buf + 8192 + wave * 1024), 16, 0, 0);
  }
  #pragma unroll
  for (int p = 0; p < 2; ++p) {
    const int8_t* g = Bw + b_base + (size_t)(p * 128 + trow) * K_DIM + ks + scol;
    __builtin_amdgcn_global_load_lds((const __attribute__((address_space(1))) void*)g,
        (__attribute__((address_space(3))) void*)(buf + 16384 + p * 8192 + wave * 1024), 16, 0, 0);
  }
}

__device__ __forceinline__ i32x4 mfma_i8(i32x4 a, i32x4 b, i32x4 c) {
  return __builtin_amdgcn_mfma_i32_16x16x64_i8(a, b, c, 0, 0, 0);
}

// compute one half-tile: 4 B ds_reads, then A ping-pong (read mi+1 under MFMA mi)
__device__ __forceinline__ void compute_half(
    const int8_t* __restrict__ buf, const int* arow, const int* brow,
    i32x4 (&acch)[4][4], i32x4 (&accl)[4][4]) {
  const int8_t* pAh = buf;
  const int8_t* pAl = buf + 8192;
  const int8_t* pB  = buf + 16384;
  i32x4 bf[4];
  #pragma unroll
  for (int ni = 0; ni < 4; ++ni) bf[ni] = *(const i32x4*)(pB + brow[ni]);
  i32x4 cah = *(const i32x4*)(pAh + arow[0]);
  i32x4 cal = *(const i32x4*)(pAl + arow[0]);
  #pragma unroll
  for (int mi = 0; mi < 4; ++mi) {
    i32x4 nah = cah, nal = cal;
    if (mi < 3) {
      nah = *(const i32x4*)(pAh + arow[mi + 1]);
      nal = *(const i32x4*)(pAl + arow[mi + 1]);
    }
    __builtin_amdgcn_s_setprio(1);
    #pragma unroll
    for (int ni = 0; ni < 4; ++ni)
      acch[mi][ni] = mfma_i8(cah, bf[ni], acch[mi][ni]);
    #pragma unroll
    for (int ni = 0; ni < 4; ++ni)
      accl[mi][ni] = mfma_i8(cal, bf[ni], accl[mi][ni]);
    __builtin_amdgcn_s_setprio(0);
    cah = nah; cal = nal;
  }
}

#define VMW(n) asm volatile("s_waitcnt vmcnt(" #n ")" ::: "memory")

__global__ __launch_bounds__(512, 2) void qgemm_kernel(
    const int8_t* __restrict__ Ah, const int8_t* __restrict__ Al,
    const int8_t* __restrict__ Bw, const float* __restrict__ xs,
    const float* __restrict__ rowsum, const float* __restrict__ scale,
    const float* __restrict__ zero, const float* __restrict__ bias,
    float* __restrict__ out) {
  extern __shared__ int8_t smem[];  // 4 x 32KB ring

  const int tid = threadIdx.x;
  const int wave = tid >> 6;
  const int lane = tid & 63;

  // XCD-chunked + grouped mapping: nwg=2752=8*344
  const int bid = blockIdx.x;
  const int wg = (bid & 7) * 344 + (bid >> 3);
  const int group = wg / 344;
  const int rem = wg % 344;
  const int bm = group * 8 + (rem & 7);  // 0..63 (M/128)
  const int bn = rem >> 3;               // 0..42 (N/256)

  const int wr = wave >> 2;  // 0..1: 64-row half of 128
  const int wc = wave & 3;   // 0..3: 64-col quarter of 256

  i32x4 acch[4][4], accl[4][4];
  #pragma unroll
  for (int i = 0; i < 4; ++i)
    #pragma unroll
    for (int j = 0; j < 4; ++j) {
      acch[i][j] = (i32x4){0, 0, 0, 0};
      accl[i][j] = (i32x4){0, 0, 0, 0};
    }

  // staging addressing (64B rows, 4 slots): thread t -> row t>>2, phys slot t&3
  const int trow = tid >> 2;                                     // 0..127
  const int scol = ((((tid & 3) - ((tid >> 3) & 3)) & 3) << 4);  // global byte col
  const size_t a_base = (size_t)(bm * 128) * K_DIM;
  const size_t b_base = (size_t)((size_t)bn * 256) * K_DIM;

  // fragment reads: phys slot = (g + (row>>1)) & 3; (row>>1)&3 == (fr>>1)&3
  const int fr = lane & 15;
  const int g = lane >> 4;
  const int scA = (((g + (fr >> 1)) & 3) << 4);

  int arow[4], brow[4];
  #pragma unroll
  for (int i = 0; i < 4; ++i) {
    arow[i] = (wr * 64 + i * 16 + fr) * 64 + scA;
    brow[i] = (wc * 64 + i * 16 + fr) * 64 + scA;
  }

  // prologue: stage 3 half-tiles ahead
  stage_half(Ah, Al, Bw, a_base, b_base, 0, trow, scol, wave, smem);
  stage_half(Ah, Al, Bw, a_base, b_base, 1, trow, scol, wave, smem);
  stage_half(Ah, Al, Bw, a_base, b_base, 2, trow, scol, wave, smem);

  #pragma unroll 1
  for (int h = 0; h < NH - 3; ++h) {
    stage_half(Ah, Al, Bw, a_base, b_base, h + 3, trow, scol, wave, smem);
    VMW(12);                       // half h's loads done; h+1..h+3 in flight
    __builtin_amdgcn_s_barrier();  // all waves' h-loads landed
    compute_half(smem + (h & 3) * BUFH, arow, brow, acch, accl);
    __builtin_amdgcn_s_barrier();  // all waves done reading ring[h&3]
  }
  // tail: drain 12 -> 8 -> 4 -> 0
  VMW(8);
  __builtin_amdgcn_s_barrier();
  compute_half(smem + ((NH - 3) & 3) * BUFH, arow, brow, acch, accl);
  __builtin_amdgcn_s_barrier();
  VMW(4);
  __builtin_amdgcn_s_barrier();
  compute_half(smem + ((NH - 2) & 3) * BUFH, arow, brow, acch, accl);
  __builtin_amdgcn_s_barrier();
  VMW(0);
  __builtin_amdgcn_s_barrier();
  compute_half(smem + ((NH - 1) & 3) * BUFH, arow, brow, acch, accl);

  // epilogue: G = xs_m*(128*Gh + Gl); y = scale*G - scale*zero*rowsum + bias
  // C/D 16x16: col = lane&15, row = (lane>>4)*4 + j
  const int row0 = bm * 128 + wr * 64;
  const int col0 = bn * 256 + wc * 64;
  float s_[4], sz_[4], b_[4];
  #pragma unroll
  for (int ni = 0; ni < 4; ++ni) {
    const int n = col0 + ni * 16 + fr;
    const float s = scale[n];
    s_[ni] = s;
    sz_[ni] = s * zero[n];
    b_[ni] = bias[n];
  }
  #pragma unroll
  for (int mi = 0; mi < 4; ++mi) {
    #pragma unroll
    for (int j = 0; j < 4; ++j) {
      const int m = row0 + mi * 16 + g * 4 + j;
      const float xsm = xs[m];
      const float rs = rowsum[m];
      float* po = out + (size_t)m * N_DIM + col0;
      #pragma unroll
      for (int ni = 0; ni < 4; ++ni) {
        const float G = xsm * (128.f * (float)acch[mi][ni][j] + (float)accl[mi][ni][j]);
        po[ni * 16 + fr] = s_[ni] * G - sz_[ni] * rs + b_[ni];
      }
    }
  }
}

// ---------------- fallback (only if workspace too small) ----------------

__global__ void fallback_kernel(const float* __restrict__ x, const int* __restrict__ w,
                                const float* __restrict__ scale, const float* __restrict__ zero,
                                const float* __restrict__ bias, float* __restrict__ out) {
  const int n = blockIdx.x * 16 + (threadIdx.x & 15);
  const int m = blockIdx.y * 16 + (threadIdx.x >> 4);
  const float z = zero[n];
  const float* xr = x + (size_t)m * K_DIM;
  const int* wr = w + (size_t)n * K_DIM;
  float acc = 0.f;
  for (int k = 0; k < K_DIM; ++k) acc += xr[k] * ((float)wr[k] - z);
  out[(size_t)m * N_DIM + n] = scale[n] * acc + bias[n];
}

// ---------------- launch ----------------

extern "C" void kernel_launch(void* const* d_in, const int* in_sizes, int n_in,
                              void* d_out, int out_size, void* d_ws, size_t ws_size,
                              hipStream_t stream) {
  const float* x     = (const float*)d_in[0];
  const int*   w     = (const int*)d_in[1];
  const float* scale = (const float*)d_in[2];
  const float* zero  = (const float*)d_in[3];
  const float* bias  = (const float*)d_in[4];
  float* out = (float*)d_out;

  const size_t n_x = (size_t)M_DIM * K_DIM;
  const size_t n_w = (size_t)N_DIM * K_DIM;
  const size_t need = n_x * 2 + n_w + (size_t)M_DIM * 8;  // ~112 MB

  if (ws_size < need) {
    dim3 gr(N_DIM / 16, M_DIM / 16);
    fallback_kernel<<<gr, 256, 0, stream>>>(x, w, scale, zero, bias, out);
    return;
  }

  int8_t* x_h = (int8_t*)d_ws;
  int8_t* x_l = x_h + n_x;
  int8_t* w_8 = x_l + n_x;
  float* rsum = (float*)(w_8 + n_w);
  float* xs   = rsum + M_DIM;

  convert_w_kernel<<<2048, 256, 0, stream>>>(w, w_8, (int)(n_w / 4));
  quantx_kernel<<<M_DIM, 256, 0, stream>>>(x, x_h, x_l, xs, rsum);

  (void)hipFuncSetAttribute((const void*)qgemm_kernel,
                            hipFuncAttributeMaxDynamicSharedMemorySize, 4 * BUFH);

  const int nblocks = (M_DIM / 128) * (N_DIM / 256);  // 64 * 43 = 2752
  qgemm_kernel<<<nblocks, 512, 4 * BUFH, stream>>>(x_h, x_l, w_8, xs, rsum,
                                                   scale, zero, bias, out);
}